// Round 18
// baseline (1476.626 us; speedup 1.0000x reference)
//
#include <hip/hip_runtime.h>
#include <math.h>

#define B_TOT 2048
#define T_LEN 512
#define HDIM 64
#define FC1 50

typedef __bf16 bf16x8 __attribute__((ext_vector_type(8)));
typedef float f32x4 __attribute__((ext_vector_type(4)));

// Fast transcendentals (no -ffast-math in harness; "/" would emit 12-inst IEEE div)
__device__ __forceinline__ float vrcp(float x) {
  float r; asm("v_rcp_f32 %0, %1" : "=v"(r) : "v"(x)); return r;
}
__device__ __forceinline__ float vexp2(float x) {
  float r; asm("v_exp_f32 %0, %1" : "=v"(r) : "v"(x)); return r;
}
__device__ __forceinline__ float sigm(float x) {
  return vrcp(1.0f + vexp2(x * -1.44269504088896340736f));
}
__device__ __forceinline__ float tanh_(float x) {
  return fmaf(2.0f, vrcp(1.0f + vexp2(x * -2.8853900817779268f)), -1.0f);
}

// lgkm-only barrier: LDS visibility without draining global queues.
#define BARRIER() asm volatile("s_waitcnt lgkmcnt(0)\n\ts_barrier" ::: "memory")
#define MFMA __builtin_amdgcn_mfma_f32_16x16x32_bf16

// Planar [16][64] bf16, 16B-chunk XOR swizzle: full-wave b128 = uniform 8 lanes/bank-group.
#define HADDR(row, chunk) (((row) << 6) + ((((chunk) ^ ((row) & 7))) << 3))

// ---------------- Single-layer A/B kernel (R17 chain, all 5 layers) ---------
// R18 finding: with the bf16-h chain, the asymmetric A/B split (913 cy/step)
// beats pair-fusion (1140 cy/layer-step): B-waves are light (no trans), so a
// SIMD hosts one heavy A-chain + one hiding B-wave, instead of two full
// chains serializing on shared pipes.
// Waves 0-3 (A, prio1): ds_read h(t-1) (2x b128), 4 gates x 2-chain MFMA
//   seeded from accx[P], fp32 gate epilogue, planar bf16 h write.
// Waves 4-7 (B): store h(t-1) to seqb (mid layers); x-MFMA (or scalar-x FMA
//   for layer 0) into accx[1-P]; prefetch x(t+3).
// In-place seq: B reads seq_{l-1}(t+3), writes seq_l(t-1) -> gap 4, rows
// block-private (proven R11-R17). LAST layer: no seq stores, A writes hT f32
// at t=T-1 (no output quantization).
// DO NOT raise __launch_bounds__ past (512,2): remat hazard (R12/R14/R15).
#define STEP(T0, P)                                                            \
  {                                                                            \
    if (isA) {                                                                 \
      bf16x8 ah0 = *(const bf16x8*)&h_b[P][HADDR(nn, cg)];                     \
      bf16x8 ah1 = *(const bf16x8*)&h_b[P][HADDR(nn, 4 + cg)];                 \
      f32x4 accs[4];                                                           \
      _Pragma("unroll")                                                        \
      for (int g = 0; g < 4; ++g) {                                            \
        f32x4 a = accx[P][g][wq * 64 + lane];                                  \
        a = MFMA(ah0, bhh[g][0], a, 0, 0, 0);                                  \
        a = MFMA(ah1, bhh[g][1], a, 0, 0, 0);                                  \
        accs[g] = a;                                                           \
      }                                                                        \
      _Pragma("unroll")                                                        \
      for (int r = 0; r < 4; ++r) {                                            \
        float iv = sigm(accs[0][r]);                                           \
        float fv = sigm(accs[1][r]);                                           \
        float gv = tanh_(accs[2][r]);                                          \
        float ov = sigm(accs[3][r]);                                           \
        cell[r] = fv * cell[r] + iv * gv;                                      \
        float hv = ov * tanh_(cell[r]);                                        \
        __bf16 h1 = (__bf16)hv;                                                \
        int mrow = 4 * cg + r;                                                 \
        h_b[1 - (P)][HADDR(mrow, uu >> 3) + (uu & 7)] = h1;                    \
        if (LAST && (T0) == T_LEN - 1)                                         \
          hT[(size_t)(bbase + mrow) * HDIM + uu] = hv;  /* f32, no quant */    \
      }                                                                        \
    } else {                                                                   \
      if (!LAST && (T0) > 0) {                                                 \
        _Pragma("unroll")                                                      \
        for (int r = 0; r < 4; ++r) {                                          \
          int mrow = 4 * cg + r;                                               \
          __bf16 h1 = h_b[P][HADDR(mrow, uu >> 3) + (uu & 7)];                 \
          seqb[((size_t)(bbase + mrow) * T_LEN + (T0) - 1) * HDIM + uu] = h1;  \
        }                                                                      \
      }                                                                        \
      if ((T0) + 1 < T_LEN) {                                                  \
        if (XIN) {                                                             \
          _Pragma("unroll")                                                    \
          for (int g = 0; g < 4; ++g) {                                        \
            f32x4 a;                                                           \
            _Pragma("unroll")                                                  \
            for (int r = 0; r < 4; ++r)                                        \
              a[r] = bias[g] + xw[g*3+0] * xr[P][r*3+0]                        \
                             + xw[g*3+1] * xr[P][r*3+1]                        \
                             + xw[g*3+2] * xr[P][r*3+2];                       \
            accx[1 - (P)][g][wq * 64 + lane] = a;                              \
          }                                                                    \
        } else {                                                               \
          _Pragma("unroll")                                                    \
          for (int g = 0; g < 4; ++g) {                                        \
            f32x4 a = {bias[g], bias[g], bias[g], bias[g]};                    \
            a = MFMA(xfr[P][0], bih[g][0], a, 0, 0, 0);                        \
            a = MFMA(xfr[P][1], bih[g][1], a, 0, 0, 0);                        \
            accx[1 - (P)][g][wq * 64 + lane] = a;                              \
          }                                                                    \
        }                                                                      \
      }                                                                        \
      {                                                                        \
        int tp = (T0) + 3; if (tp >= T_LEN) tp = T_LEN - 1;                    \
        if (XIN) {                                                             \
          _Pragma("unroll")                                                    \
          for (int r = 0; r < 4; ++r)                                          \
            _Pragma("unroll")                                                  \
            for (int i = 0; i < 3; ++i)                                        \
              xr[P][r*3+i] =                                                   \
                  x_f32[((size_t)(bbase + 4*cg + r) * T_LEN + tp) * 3 + i];    \
        } else {                                                               \
          const __bf16* px = seqb + xrow + (size_t)tp * HDIM;                  \
          xfr[P][0] = *(const bf16x8*)(px + 8 * cg);                           \
          xfr[P][1] = *(const bf16x8*)(px + 32 + 8 * cg);                      \
        }                                                                      \
      }                                                                        \
    }                                                                          \
    BARRIER();                                                                 \
  }

template<bool XIN, bool LAST>
__global__ __launch_bounds__(512, 2)   // DO NOT raise (remat hazard)
void lstm_single(const float* __restrict__ x_f32,   // XIN only: [B,T,3]
                 const float* __restrict__ w_ih,    // XIN: [256,3] else [256,64]
                 const float* __restrict__ w_hh,    // [256,64]
                 const float* __restrict__ b_ih,
                 const float* __restrict__ b_hh,
                 __bf16* __restrict__ seqb,         // [B,T,64] bf16 (in/out, in-place)
                 float* __restrict__ hT)            // LAST only: [B,64] f32
{
    const int tid  = threadIdx.x;
    const int lane = tid & 63;
    const int wv   = tid >> 6;
    const bool isA = (wv < 4);
    const int wq   = wv & 3;
    const int nn   = lane & 15;
    const int cg   = lane >> 4;
    const int bbase = blockIdx.x * 16;
    const int grow = 16 * wq + nn;
    const int uu   = grow;

    __shared__ __align__(16) __bf16 h_b[2][1024];        // 4 KB
    __shared__ __align__(16) f32x4 accx[2][4][256];      // 32 KB

    bf16x8 bhh[4][2];
    bf16x8 bih[4][2];
    float xw[12];
    float bias[4];
    if (isA) {
#pragma unroll
      for (int g = 0; g < 4; ++g)
#pragma unroll
        for (int kk = 0; kk < 2; ++kk) {
          const float* wp = w_hh + (size_t)(64 * g + grow) * 64 + kk * 32 + 8 * cg;
          bf16x8 t;
#pragma unroll
          for (int e = 0; e < 8; ++e) t[e] = (__bf16)wp[e];
          bhh[g][kk] = t;
        }
    } else {
#pragma unroll
      for (int g = 0; g < 4; ++g) {
        int row = 64 * g + grow;
        bias[g] = b_ih[row] + b_hh[row];
      }
      if (XIN) {
#pragma unroll
        for (int g = 0; g < 4; ++g)
#pragma unroll
          for (int i = 0; i < 3; ++i) xw[g * 3 + i] = w_ih[(64 * g + grow) * 3 + i];
      } else {
#pragma unroll
        for (int g = 0; g < 4; ++g)
#pragma unroll
          for (int kk = 0; kk < 2; ++kk) {
            const float* wp = w_ih + (size_t)(64 * g + grow) * 64 + kk * 32 + 8 * cg;
            bf16x8 t;
#pragma unroll
            for (int e = 0; e < 8; ++e) t[e] = (__bf16)wp[e];
            bih[g][kk] = t;
          }
      }
    }

    for (int q = tid; q < 2048; q += 512)
      ((__bf16*)h_b)[q] = (__bf16)0.f;

    float cell[4] = {0.f, 0.f, 0.f, 0.f};
    const size_t xrow = (size_t)(bbase + nn) * T_LEN * HDIM;
    bf16x8 xfr[2][2];
    float xr[2][12];

    if (!isA) {
      if (XIN) {
        float x0[12];
#pragma unroll
        for (int r = 0; r < 4; ++r)
#pragma unroll
          for (int i = 0; i < 3; ++i)
            x0[r*3+i] = x_f32[((size_t)(bbase + 4*cg + r) * T_LEN + 0) * 3 + i];
#pragma unroll
        for (int g = 0; g < 4; ++g) {
          f32x4 a;
#pragma unroll
          for (int r = 0; r < 4; ++r)
            a[r] = bias[g] + xw[g*3+0]*x0[r*3+0] + xw[g*3+1]*x0[r*3+1] + xw[g*3+2]*x0[r*3+2];
          accx[0][g][wq * 64 + lane] = a;
        }
#pragma unroll
        for (int p = 0; p < 2; ++p)
#pragma unroll
          for (int r = 0; r < 4; ++r)
#pragma unroll
            for (int i = 0; i < 3; ++i)
              xr[p][r*3+i] = x_f32[((size_t)(bbase + 4*cg + r) * T_LEN + (p + 1)) * 3 + i];
      } else {
        const __bf16* px = seqb + xrow;
        bf16x8 x0a = *(const bf16x8*)(px + 8 * cg);
        bf16x8 x0b = *(const bf16x8*)(px + 32 + 8 * cg);
#pragma unroll
        for (int g = 0; g < 4; ++g) {
          f32x4 a = {bias[g], bias[g], bias[g], bias[g]};
          a = MFMA(x0a, bih[g][0], a, 0, 0, 0);
          a = MFMA(x0b, bih[g][1], a, 0, 0, 0);
          accx[0][g][wq * 64 + lane] = a;
        }
#pragma unroll
        for (int p = 0; p < 2; ++p) {
          const __bf16* pq = seqb + xrow + (size_t)(p + 1) * HDIM;
          xfr[p][0] = *(const bf16x8*)(pq + 8 * cg);
          xfr[p][1] = *(const bf16x8*)(pq + 32 + 8 * cg);
        }
      }
    }
    __syncthreads();

    if (isA) __builtin_amdgcn_s_setprio(1);
    for (int t = 0; t < T_LEN; t += 2) {
      STEP(t, 0);
      STEP(t + 1, 1);
    }
    if (isA) __builtin_amdgcn_s_setprio(0);

    // tail: store h(T-1) (in h_b[0] after STEP(511, P=1))
    if (!LAST && !isA) {
#pragma unroll
      for (int r = 0; r < 4; ++r) {
        int mrow = 4 * cg + r;
        __bf16 h1 = h_b[0][HADDR(mrow, uu >> 3) + (uu & 7)];
        seqb[((size_t)(bbase + mrow) * T_LEN + (T_LEN - 1)) * HDIM + uu] = h1;
      }
    }
}

// FC head: out[b] = fc2_b + fc2_w . relu(fc1_b + fc1_w . hT[b]); hT is f32.
__global__ __launch_bounds__(256, 1)
void fc_head(const float* __restrict__ hT,
             const float* __restrict__ fc1_w, const float* __restrict__ fc1_b,
             const float* __restrict__ fc2_w, const float* __restrict__ fc2_b,
             float* __restrict__ out)
{
    __shared__ float w1[FC1 * HDIM];
    __shared__ float b1[FC1];
    __shared__ float w2[FC1];
    const int tid = threadIdx.x;
    for (int i = tid; i < FC1 * HDIM; i += 256) w1[i] = fc1_w[i];
    if (tid < FC1) { b1[tid] = fc1_b[tid]; w2[tid] = fc2_w[tid]; }
    __syncthreads();

    const int b = blockIdx.x * 256 + tid;
    float h[HDIM];
    const float4* hp = (const float4*)(hT + (size_t)b * HDIM);
#pragma unroll
    for (int q = 0; q < 16; ++q) {
      float4 v = hp[q];
      h[q*4+0] = v.x; h[q*4+1] = v.y; h[q*4+2] = v.z; h[q*4+3] = v.w;
    }
    float acc2 = fc2_b[0];
    for (int m = 0; m < FC1; ++m) {
      float a = b1[m];
#pragma unroll
      for (int q = 0; q < HDIM; ++q) a += w1[m * HDIM + q] * h[q];
      acc2 += w2[m] * fmaxf(a, 0.0f);
    }
    out[b] = acc2;
}

extern "C" void kernel_launch(void* const* d_in, const int* in_sizes, int n_in,
                              void* d_out, int out_size, void* d_ws, size_t ws_size,
                              hipStream_t stream) {
    const float* x         = (const float*)d_in[0];
    const float* w_ih0     = (const float*)d_in[1];
    const float* w_ih_rest = (const float*)d_in[2];
    const float* w_hh      = (const float*)d_in[3];
    const float* b_ih      = (const float*)d_in[4];
    const float* b_hh      = (const float*)d_in[5];
    const float* fc1_w     = (const float*)d_in[6];
    const float* fc1_b     = (const float*)d_in[7];
    const float* fc2_w     = (const float*)d_in[8];
    const float* fc2_b     = (const float*)d_in[9];
    float* out = (float*)d_out;

    __bf16* seqb = (__bf16*)d_ws;                                   // 128 MiB
    float* hT = (float*)(seqb + (size_t)B_TOT * T_LEN * HDIM);      // 512 KiB

    dim3 grid(B_TOT / 16), block(512);
    // layer 0: scalar-x input, writes seq (bf16)
    lstm_single<true, false><<<grid, block, 0, stream>>>(
        x, w_ih0, w_hh, b_ih, b_hh, seqb, hT);
    // layers 1-3: read/write seq in-place (gap-4 trailing)
    for (int l = 1; l < 4; ++l) {
      lstm_single<false, false><<<grid, block, 0, stream>>>(
          nullptr,
          w_ih_rest + (size_t)(l - 1) * 256 * HDIM,
          w_hh + (size_t)l * 256 * HDIM,
          b_ih + (size_t)l * 256,
          b_hh + (size_t)l * 256,
          seqb, hT);
    }
    // layer 4: no seq stores; A-waves write hT f32 at t=T-1
    lstm_single<false, true><<<grid, block, 0, stream>>>(
        nullptr,
        w_ih_rest + (size_t)3 * 256 * HDIM,
        w_hh + (size_t)4 * 256 * HDIM,
        b_ih + (size_t)4 * 256,
        b_hh + (size_t)4 * 256,
        seqb, hT);
    fc_head<<<dim3(B_TOT / 256), dim3(256), 0, stream>>>(
        hT, fc1_w, fc1_b, fc2_w, fc2_b, out);
}

// Round 19
// 1216.568 us; speedup vs baseline: 1.2138x; 1.2138x over previous
//
#include <hip/hip_runtime.h>
#include <math.h>

#define B_TOT 2048
#define T_LEN 512
#define HDIM 64
#define FC1 50
#define NSUP 514   // skew-2 pair: 512 + 2

typedef __bf16 bf16x8 __attribute__((ext_vector_type(8)));
typedef float f32x4 __attribute__((ext_vector_type(4)));

// Fast transcendentals (no -ffast-math in harness; "/" would emit 12-inst IEEE div)
__device__ __forceinline__ float vrcp(float x) {
  float r; asm("v_rcp_f32 %0, %1" : "=v"(r) : "v"(x)); return r;
}
__device__ __forceinline__ float vexp2(float x) {
  float r; asm("v_exp_f32 %0, %1" : "=v"(r) : "v"(x)); return r;
}
__device__ __forceinline__ float sigm(float x) {
  return vrcp(1.0f + vexp2(x * -1.44269504088896340736f));
}
__device__ __forceinline__ float tanh_(float x) {
  return fmaf(2.0f, vrcp(1.0f + vexp2(x * -2.8853900817779268f)), -1.0f);
}

// lgkm-only barrier: LDS visibility without draining global queues.
#define BARRIER() asm volatile("s_waitcnt lgkmcnt(0)\n\ts_barrier" ::: "memory")
#define MFMA __builtin_amdgcn_mfma_f32_16x16x32_bf16

// Planar [16][64] bf16, 16B-chunk XOR swizzle: full-wave b128 = uniform 8 lanes/bank-group.
#define HADDR(row, chunk) (((row) << 6) + ((((chunk) ^ ((row) & 7))) << 3))

// ---------- Skew-2 pair kernel (R17 structure, bf16 h) ----------------------
// Config lesson (R18): layers that must store seq are cheapest in PAIRS
// (1140 cy/layer vs 1617 single-with-stores); the store-free last layer is
// cheapest as an A/B single (950 cy). This file = R17's proven 1187us config
// + R19 micro: set1 seq-stores via running pointers (no per-store mul chain).
// DO NOT raise __launch_bounds__ past (512,2): (512,4)/(1024,*) trigger
// weight remat (R12/R14/R15: VGPR collapse, FETCH x40, 2-5x slowdowns).
#define SUPERQ(N_, P_)                                                         \
  {                                                                            \
    if (set == 0) {                                                            \
      if ((N_) < T_LEN) {                                                      \
        bf16x8 ah0 = *(const bf16x8*)&Hb[0][1 - (P_)][HADDR(nn, cg)];          \
        bf16x8 ah1 = *(const bf16x8*)&Hb[0][1 - (P_)][HADDR(nn, 4 + cg)];      \
        f32x4 accs[4];                                                         \
        _Pragma("unroll") for (int g = 0; g < 4; ++g) {                        \
          f32x4 a = xacc[P_][g];                                               \
          a = MFMA(ah0, bhh[g][0], a, 0, 0, 0);                                \
          a = MFMA(ah1, bhh[g][1], a, 0, 0, 0);                                \
          accs[g] = a;                                                         \
        }                                                                      \
        _Pragma("unroll") for (int r = 0; r < 4; ++r) {                        \
          float iv = sigm(accs[0][r]);                                         \
          float fv = sigm(accs[1][r]);                                         \
          float gv = tanh_(accs[2][r]);                                        \
          float ov = sigm(accs[3][r]);                                         \
          cell[r] = fv * cell[r] + iv * gv;                                    \
          float hv = ov * tanh_(cell[r]);                                      \
          __bf16 h1 = (__bf16)hv;                                              \
          int mrow = 4 * cg + r;                                               \
          Hb[0][P_][HADDR(mrow, uu >> 3) + (uu & 7)] = h1;                     \
        }                                                                      \
      }                                                                        \
      /* tail: x-seed for t = N_+1 */                                         \
      if ((N_) + 1 < T_LEN) {                                                  \
        if (XIN) {                                                             \
          _Pragma("unroll") for (int g = 0; g < 4; ++g) {                      \
            f32x4 a;                                                           \
            _Pragma("unroll") for (int r = 0; r < 4; ++r)                      \
              a[r] = bias[g] + xw[g*3+0] * xr[P_][r*3+0]                       \
                             + xw[g*3+1] * xr[P_][r*3+1]                       \
                             + xw[g*3+2] * xr[P_][r*3+2];                      \
            xacc[1 - (P_)][g] = a;                                             \
          }                                                                    \
        } else {                                                               \
          _Pragma("unroll") for (int g = 0; g < 4; ++g) {                      \
            f32x4 a = {bias[g], bias[g], bias[g], bias[g]};                    \
            a = MFMA(xfr[P_][0], bih[g][0], a, 0, 0, 0);                       \
            a = MFMA(xfr[P_][1], bih[g][1], a, 0, 0, 0);                       \
            xacc[1 - (P_)][g] = a;                                             \
          }                                                                    \
        }                                                                      \
      }                                                                        \
      {                                                                        \
        int tp = (N_) + 3; if (tp > T_LEN - 1) tp = T_LEN - 1;                 \
        if (XIN) {                                                             \
          _Pragma("unroll") for (int r = 0; r < 4; ++r)                        \
            _Pragma("unroll") for (int i = 0; i < 3; ++i)                      \
              xr[P_][r*3+i] =                                                  \
                  x_f32[((size_t)(bbase + 4*cg + r) * T_LEN + tp) * 3 + i];    \
        } else {                                                               \
          const __bf16* px = seqb + xrow + (size_t)tp * HDIM;                  \
          xfr[P_][0] = *(const bf16x8*)(px + 8 * cg);                          \
          xfr[P_][1] = *(const bf16x8*)(px + 32 + 8 * cg);                     \
        }                                                                      \
      }                                                                        \
    } else {                                                                   \
      if ((N_) >= 2) {                                                         \
        bf16x8 ah0 = *(const bf16x8*)&Hb[1][1 - (P_)][HADDR(nn, cg)];          \
        bf16x8 ah1 = *(const bf16x8*)&Hb[1][1 - (P_)][HADDR(nn, 4 + cg)];      \
        f32x4 accs[4];                                                         \
        _Pragma("unroll") for (int g = 0; g < 4; ++g) {                        \
          f32x4 a = xacc[P_][g];                                               \
          a = MFMA(ah0, bhh[g][0], a, 0, 0, 0);                                \
          a = MFMA(ah1, bhh[g][1], a, 0, 0, 0);                                \
          accs[g] = a;                                                         \
        }                                                                      \
        _Pragma("unroll") for (int r = 0; r < 4; ++r) {                        \
          float iv = sigm(accs[0][r]);                                         \
          float fv = sigm(accs[1][r]);                                         \
          float gv = tanh_(accs[2][r]);                                        \
          float ov = sigm(accs[3][r]);                                         \
          cell[r] = fv * cell[r] + iv * gv;                                    \
          float hv = ov * tanh_(cell[r]);                                      \
          __bf16 h1 = (__bf16)hv;                                              \
          int mrow = 4 * cg + r;                                               \
          Hb[1][P_][HADDR(mrow, uu >> 3) + (uu & 7)] = h1;                     \
          *sp[r] = h1;            /* running pointer store (tl = N_-2) */      \
        }                                                                      \
        _Pragma("unroll") for (int r = 0; r < 4; ++r) sp[r] += HDIM;           \
      }                                                                        \
      /* tail: x-seed for t = N_-1 from upstream h0(N_-1), pre-barrier data */ \
      if ((N_) >= 1 && (N_) - 1 < T_LEN) {                                     \
        bf16x8 xh0 = *(const bf16x8*)&Hb[0][1 - (P_)][HADDR(nn, cg)];          \
        bf16x8 xh1 = *(const bf16x8*)&Hb[0][1 - (P_)][HADDR(nn, 4 + cg)];      \
        _Pragma("unroll") for (int g = 0; g < 4; ++g) {                        \
          f32x4 a = {bias[g], bias[g], bias[g], bias[g]};                      \
          a = MFMA(xh0, bih[g][0], a, 0, 0, 0);                                \
          a = MFMA(xh1, bih[g][1], a, 0, 0, 0);                                \
          xacc[1 - (P_)][g] = a;                                               \
        }                                                                      \
      }                                                                        \
    }                                                                          \
    BARRIER();                                                                 \
  }

template<bool XIN>
__global__ __launch_bounds__(512, 2)   // DO NOT raise (remat hazard)
void lstm_pairq(const float* __restrict__ x_f32,
                const float* __restrict__ w_ih0,
                const float* __restrict__ w_ih_rest,
                const float* __restrict__ w_hh,
                const float* __restrict__ b_ih,
                const float* __restrict__ b_hh,
                __bf16* __restrict__ seqb,
                int L0)
{
  const int tid  = threadIdx.x;
  const int lane = tid & 63;
  const int wv   = tid >> 6;
  const int set  = wv >> 2;       // 0,1 (wave-uniform)
  const int wq   = wv & 3;
  const int nn   = lane & 15;
  const int cg   = lane >> 4;
  const int bbase = blockIdx.x * 16;
  const int grow = 16 * wq + nn;
  const int uu   = grow;
  const int layer = L0 + set;

  __shared__ __align__(16) __bf16 Hb[2][2][1024];  // [set][parity], 4 KB

  bf16x8 bhh[4][2];
#pragma unroll
  for (int g = 0; g < 4; ++g)
#pragma unroll
    for (int kk = 0; kk < 2; ++kk) {
      const float* wp = w_hh + (size_t)layer * 256 * 64
                      + (size_t)(64 * g + grow) * 64 + kk * 32 + 8 * cg;
      bf16x8 t;
#pragma unroll
      for (int e = 0; e < 8; ++e) t[e] = (__bf16)wp[e];
      bhh[g][kk] = t;
    }
  bf16x8 bih[4][2];
  float xw[12];
  if (XIN && set == 0) {
#pragma unroll
    for (int g = 0; g < 4; ++g)
#pragma unroll
      for (int i = 0; i < 3; ++i) xw[g * 3 + i] = w_ih0[(64 * g + grow) * 3 + i];
  } else {
    const float* wih_l = w_ih_rest + (size_t)(layer - 1) * 256 * 64;
#pragma unroll
    for (int g = 0; g < 4; ++g)
#pragma unroll
      for (int kk = 0; kk < 2; ++kk) {
        const float* wp = wih_l + (size_t)(64 * g + grow) * 64 + kk * 32 + 8 * cg;
        bf16x8 t;
#pragma unroll
        for (int e = 0; e < 8; ++e) t[e] = (__bf16)wp[e];
        bih[g][kk] = t;
      }
  }
  float bias[4];
#pragma unroll
  for (int g = 0; g < 4; ++g) {
    int row = layer * 256 + 64 * g + grow;
    bias[g] = b_ih[row] + b_hh[row];
  }

  for (int q = tid; q < 4 * 1024; q += 512)
    ((__bf16*)Hb)[q] = (__bf16)0.f;

  float cell[4] = {0.f, 0.f, 0.f, 0.f};
  const size_t xrow = (size_t)(bbase + nn) * T_LEN * HDIM;

  f32x4 xacc[2][4];    // register x-seed, parity-indexed (macro-literal P_ only)
  float xr[2][12];     // set0 XIN queue
  bf16x8 xfr[2][2];    // set0 GIN queue (direct bf16 fragments)
  __bf16* sp[4];       // set1 running store pointers (advance +HDIM/superstep)

  if (set == 1) {
#pragma unroll
    for (int r = 0; r < 4; ++r) {
      int mrow = 4 * cg + r;
      sp[r] = seqb + (size_t)(bbase + mrow) * T_LEN * HDIM + uu;
    }
  }

  if (set == 0) {
    if (XIN) {
      float x0[12];
#pragma unroll
      for (int r = 0; r < 4; ++r)
#pragma unroll
        for (int i = 0; i < 3; ++i)
          x0[r*3+i] = x_f32[((size_t)(bbase + 4*cg + r) * T_LEN + 0) * 3 + i];
#pragma unroll
      for (int g = 0; g < 4; ++g) {
        f32x4 a;
#pragma unroll
        for (int r = 0; r < 4; ++r)
          a[r] = bias[g] + xw[g*3+0]*x0[r*3+0] + xw[g*3+1]*x0[r*3+1] + xw[g*3+2]*x0[r*3+2];
        xacc[0][g] = a;
      }
#pragma unroll
      for (int p = 0; p < 2; ++p)
#pragma unroll
        for (int r = 0; r < 4; ++r)
#pragma unroll
          for (int i = 0; i < 3; ++i)
            xr[p][r*3+i] = x_f32[((size_t)(bbase + 4*cg + r) * T_LEN + (p + 1)) * 3 + i];
    } else {
      const __bf16* px = seqb + xrow;
      bf16x8 x0a = *(const bf16x8*)(px + 8 * cg);
      bf16x8 x0b = *(const bf16x8*)(px + 32 + 8 * cg);
#pragma unroll
      for (int g = 0; g < 4; ++g) {
        f32x4 a = {bias[g], bias[g], bias[g], bias[g]};
        a = MFMA(x0a, bih[g][0], a, 0, 0, 0);
        a = MFMA(x0b, bih[g][1], a, 0, 0, 0);
        xacc[0][g] = a;
      }
#pragma unroll
      for (int p = 0; p < 2; ++p) {
        const __bf16* pq = seqb + xrow + (size_t)(p + 1) * HDIM;
        xfr[p][0] = *(const bf16x8*)(pq + 8 * cg);
        xfr[p][1] = *(const bf16x8*)(pq + 32 + 8 * cg);
      }
    }
  }
  __syncthreads();

  for (int n = 0; n < NSUP; n += 2) {
    SUPERQ(n,     0);
    SUPERQ(n + 1, 1);
  }
}

// -------------- Single-layer kernel (layer 4, bf16 h; writes hT f32) --------
#define STEP(T0, P)                                                            \
  {                                                                            \
    if (isA) {                                                                 \
      bf16x8 ah0 = *(const bf16x8*)&h_b[P][HADDR(nn, cg)];                     \
      bf16x8 ah1 = *(const bf16x8*)&h_b[P][HADDR(nn, 4 + cg)];                 \
      f32x4 accs[4];                                                           \
      _Pragma("unroll")                                                        \
      for (int g = 0; g < 4; ++g) {                                            \
        f32x4 a = accx[P][g][wq * 64 + lane];                                  \
        a = MFMA(ah0, bhh[g][0], a, 0, 0, 0);                                  \
        a = MFMA(ah1, bhh[g][1], a, 0, 0, 0);                                  \
        accs[g] = a;                                                           \
      }                                                                        \
      _Pragma("unroll")                                                        \
      for (int r = 0; r < 4; ++r) {                                            \
        float iv = sigm(accs[0][r]);                                           \
        float fv = sigm(accs[1][r]);                                           \
        float gv = tanh_(accs[2][r]);                                          \
        float ov = sigm(accs[3][r]);                                           \
        cell[r] = fv * cell[r] + iv * gv;                                      \
        float hv = ov * tanh_(cell[r]);                                        \
        __bf16 h1 = (__bf16)hv;                                                \
        int mrow = 4 * cg + r;                                                 \
        h_b[1 - (P)][HADDR(mrow, uu >> 3) + (uu & 7)] = h1;                    \
        if ((T0) == T_LEN - 1)                                                 \
          hT[(size_t)(bbase + mrow) * HDIM + uu] = hv;  /* f32, no quant */    \
      }                                                                        \
    } else {                                                                   \
      if ((T0) + 1 < T_LEN) {                                                  \
        _Pragma("unroll")                                                      \
        for (int g = 0; g < 4; ++g) {                                          \
          f32x4 a = {bias[g], bias[g], bias[g], bias[g]};                      \
          a = MFMA(xfr[P][0], bih[g][0], a, 0, 0, 0);                          \
          a = MFMA(xfr[P][1], bih[g][1], a, 0, 0, 0);                          \
          accx[1 - (P)][g][wq * 64 + lane] = a;                                \
        }                                                                      \
      }                                                                        \
      {                                                                        \
        int tp = (T0) + 3; if (tp >= T_LEN) tp = T_LEN - 1;                    \
        const __bf16* px = seqb + xrow + (size_t)tp * HDIM;                    \
        xfr[P][0] = *(const bf16x8*)(px + 8 * cg);                             \
        xfr[P][1] = *(const bf16x8*)(px + 32 + 8 * cg);                        \
      }                                                                        \
    }                                                                          \
    BARRIER();                                                                 \
  }

__global__ __launch_bounds__(512, 2)
void lstm_single(const float* __restrict__ w_ih,
                 const float* __restrict__ w_hh,
                 const float* __restrict__ b_ih,
                 const float* __restrict__ b_hh,
                 const __bf16* __restrict__ seqb,
                 float* __restrict__ hT)
{
    const int tid  = threadIdx.x;
    const int lane = tid & 63;
    const int wv   = tid >> 6;
    const bool isA = (wv < 4);
    const int wq   = wv & 3;
    const int nn   = lane & 15;
    const int cg   = lane >> 4;
    const int bbase = blockIdx.x * 16;
    const int grow = 16 * wq + nn;
    const int uu   = grow;

    __shared__ __align__(16) __bf16 h_b[2][1024];        // 4 KB
    __shared__ __align__(16) f32x4 accx[2][4][256];      // 32 KB

    bf16x8 bhh[4][2];
    bf16x8 bih[4][2];
    float bias[4];
    if (isA) {
#pragma unroll
      for (int g = 0; g < 4; ++g)
#pragma unroll
        for (int kk = 0; kk < 2; ++kk) {
          const float* wp = w_hh + (size_t)(64 * g + grow) * 64 + kk * 32 + 8 * cg;
          bf16x8 t;
#pragma unroll
          for (int e = 0; e < 8; ++e) t[e] = (__bf16)wp[e];
          bhh[g][kk] = t;
        }
    } else {
#pragma unroll
      for (int g = 0; g < 4; ++g) {
        int row = 64 * g + grow;
        bias[g] = b_ih[row] + b_hh[row];
      }
#pragma unroll
      for (int g = 0; g < 4; ++g)
#pragma unroll
        for (int kk = 0; kk < 2; ++kk) {
          const float* wp = w_ih + (size_t)(64 * g + grow) * 64 + kk * 32 + 8 * cg;
          bf16x8 t;
#pragma unroll
          for (int e = 0; e < 8; ++e) t[e] = (__bf16)wp[e];
          bih[g][kk] = t;
        }
    }

    for (int q = tid; q < 2048; q += 512)
      ((__bf16*)h_b)[q] = (__bf16)0.f;

    float cell[4] = {0.f, 0.f, 0.f, 0.f};
    const size_t xrow = (size_t)(bbase + nn) * T_LEN * HDIM;
    bf16x8 xfr[2][2];

    if (!isA) {
      const __bf16* px = seqb + xrow;
      bf16x8 x0a = *(const bf16x8*)(px + 8 * cg);
      bf16x8 x0b = *(const bf16x8*)(px + 32 + 8 * cg);
#pragma unroll
      for (int g = 0; g < 4; ++g) {
        f32x4 a = {bias[g], bias[g], bias[g], bias[g]};
        a = MFMA(x0a, bih[g][0], a, 0, 0, 0);
        a = MFMA(x0b, bih[g][1], a, 0, 0, 0);
        accx[0][g][wq * 64 + lane] = a;
      }
#pragma unroll
      for (int p = 0; p < 2; ++p) {
        const __bf16* pq = seqb + xrow + (size_t)(p + 1) * HDIM;
        xfr[p][0] = *(const bf16x8*)(pq + 8 * cg);
        xfr[p][1] = *(const bf16x8*)(pq + 32 + 8 * cg);
      }
    }
    __syncthreads();

    if (isA) __builtin_amdgcn_s_setprio(1);
    for (int t = 0; t < T_LEN; t += 2) {
      STEP(t, 0);
      STEP(t + 1, 1);
    }
    if (isA) __builtin_amdgcn_s_setprio(0);
}

// FC head: out[b] = fc2_b + fc2_w . relu(fc1_b + fc1_w . hT[b]); hT is f32.
__global__ __launch_bounds__(256, 1)
void fc_head(const float* __restrict__ hT,
             const float* __restrict__ fc1_w, const float* __restrict__ fc1_b,
             const float* __restrict__ fc2_w, const float* __restrict__ fc2_b,
             float* __restrict__ out)
{
    __shared__ float w1[FC1 * HDIM];
    __shared__ float b1[FC1];
    __shared__ float w2[FC1];
    const int tid = threadIdx.x;
    for (int i = tid; i < FC1 * HDIM; i += 256) w1[i] = fc1_w[i];
    if (tid < FC1) { b1[tid] = fc1_b[tid]; w2[tid] = fc2_w[tid]; }
    __syncthreads();

    const int b = blockIdx.x * 256 + tid;
    float h[HDIM];
    const float4* hp = (const float4*)(hT + (size_t)b * HDIM);
#pragma unroll
    for (int q = 0; q < 16; ++q) {
      float4 v = hp[q];
      h[q*4+0] = v.x; h[q*4+1] = v.y; h[q*4+2] = v.z; h[q*4+3] = v.w;
    }
    float acc2 = fc2_b[0];
    for (int m = 0; m < FC1; ++m) {
      float a = b1[m];
#pragma unroll
      for (int q = 0; q < HDIM; ++q) a += w1[m * HDIM + q] * h[q];
      acc2 += w2[m] * fmaxf(a, 0.0f);
    }
    out[b] = acc2;
}

extern "C" void kernel_launch(void* const* d_in, const int* in_sizes, int n_in,
                              void* d_out, int out_size, void* d_ws, size_t ws_size,
                              hipStream_t stream) {
    const float* x         = (const float*)d_in[0];
    const float* w_ih0     = (const float*)d_in[1];
    const float* w_ih_rest = (const float*)d_in[2];
    const float* w_hh      = (const float*)d_in[3];
    const float* b_ih      = (const float*)d_in[4];
    const float* b_hh      = (const float*)d_in[5];
    const float* fc1_w     = (const float*)d_in[6];
    const float* fc1_b     = (const float*)d_in[7];
    const float* fc2_w     = (const float*)d_in[8];
    const float* fc2_b     = (const float*)d_in[9];
    float* out = (float*)d_out;

    __bf16* seqb = (__bf16*)d_ws;                                   // 128 MiB
    float* hT = (float*)(seqb + (size_t)B_TOT * T_LEN * HDIM);      // 512 KiB

    dim3 grid(B_TOT / 16), block(512);
    // layers 0+1, skew-2 pair; writes seq1 (bf16)
    lstm_pairq<true><<<grid, block, 0, stream>>>(
        x, w_ih0, w_ih_rest, w_hh, b_ih, b_hh, seqb, 0);
    // layers 2+3, skew-2 pair; reads seq1 / writes seq3 in-place (gap >= 5)
    lstm_pairq<false><<<grid, block, 0, stream>>>(
        x, w_ih0, w_ih_rest, w_hh, b_ih, b_hh, seqb, 2);
    // layer 4; reads seq3, writes hT f32 (A-wave epilogue, no quantization)
    lstm_single<<<grid, block, 0, stream>>>(
        w_ih_rest + (size_t)3 * 256 * HDIM,
        w_hh + (size_t)4 * 256 * HDIM,
        b_ih + (size_t)4 * 256,
        b_hh + (size_t)4 * 256,
        seqb, hT);
    fc_head<<<dim3(B_TOT / 256), dim3(256), 0, stream>>>(
        hT, fc1_w, fc1_b, fc2_w, fc2_b, out);
}

// Round 20
// 1185.446 us; speedup vs baseline: 1.2456x; 1.0263x over previous
//
#include <hip/hip_runtime.h>
#include <math.h>

#define B_TOT 2048
#define T_LEN 512
#define HDIM 64
#define FC1 50
#define NSUP 514   // skew-2 pair: 512 + 2

typedef __bf16 bf16x8 __attribute__((ext_vector_type(8)));
typedef float f32x4 __attribute__((ext_vector_type(4)));

// Fast transcendentals (no -ffast-math in harness; "/" would emit 12-inst IEEE div)
__device__ __forceinline__ float vrcp(float x) {
  float r; asm("v_rcp_f32 %0, %1" : "=v"(r) : "v"(x)); return r;
}
__device__ __forceinline__ float vexp2(float x) {
  float r; asm("v_exp_f32 %0, %1" : "=v"(r) : "v"(x)); return r;
}
__device__ __forceinline__ float sigm(float x) {
  return vrcp(1.0f + vexp2(x * -1.44269504088896340736f));
}
__device__ __forceinline__ float tanh_(float x) {
  return fmaf(2.0f, vrcp(1.0f + vexp2(x * -2.8853900817779268f)), -1.0f);
}

// lgkm-only barrier: LDS visibility without draining global queues.
#define BARRIER() asm volatile("s_waitcnt lgkmcnt(0)\n\ts_barrier" ::: "memory")
#define MFMA __builtin_amdgcn_mfma_f32_16x16x32_bf16

// Planar [16][64] bf16, 16B-chunk XOR swizzle: full-wave b128 = uniform 8 lanes/bank-group.
#define HADDR(row, chunk) (((row) << 6) + ((((chunk) ^ ((row) & 7))) << 3))

// ---------- Skew-2 pair kernel (R17-exact, FINAL) ---------------------------
// Final config (R17, 1187us): layers storing seq run in PAIRS (1140cy/layer);
// the store-free last layer runs as an A/B single (950cy). h carried as plain
// bf16 (hi/lo split was pure waste: absmax unchanged at 1.2207e-4, which is
// weight-quantization-dominated). Cell state f32 in registers.
// Rejected by measurement: 3-set fusion (R7/R10), cross-block rings (R6),
// TLP oversubscription (R14), per-wave 2-tile ILP (R15), chain split+desync
// (R16), all-singles (R18), running-pointer stores (R19).
// DO NOT raise __launch_bounds__ past (512,2): (512,4)/(1024,*) trigger
// weight remat (R12/R14/R15: VGPR collapse, FETCH x40, 2-5x slowdowns).
#define SUPERQ(N_, P_)                                                         \
  {                                                                            \
    if (set == 0) {                                                            \
      if ((N_) < T_LEN) {                                                      \
        bf16x8 ah0 = *(const bf16x8*)&Hb[0][1 - (P_)][HADDR(nn, cg)];          \
        bf16x8 ah1 = *(const bf16x8*)&Hb[0][1 - (P_)][HADDR(nn, 4 + cg)];      \
        f32x4 accs[4];                                                         \
        _Pragma("unroll") for (int g = 0; g < 4; ++g) {                        \
          f32x4 a = xacc[P_][g];                                               \
          a = MFMA(ah0, bhh[g][0], a, 0, 0, 0);                                \
          a = MFMA(ah1, bhh[g][1], a, 0, 0, 0);                                \
          accs[g] = a;                                                         \
        }                                                                      \
        _Pragma("unroll") for (int r = 0; r < 4; ++r) {                        \
          float iv = sigm(accs[0][r]);                                         \
          float fv = sigm(accs[1][r]);                                         \
          float gv = tanh_(accs[2][r]);                                        \
          float ov = sigm(accs[3][r]);                                         \
          cell[r] = fv * cell[r] + iv * gv;                                    \
          float hv = ov * tanh_(cell[r]);                                      \
          __bf16 h1 = (__bf16)hv;                                              \
          int mrow = 4 * cg + r;                                               \
          Hb[0][P_][HADDR(mrow, uu >> 3) + (uu & 7)] = h1;                     \
        }                                                                      \
      }                                                                        \
      /* tail: x-seed for t = N_+1 */                                         \
      if ((N_) + 1 < T_LEN) {                                                  \
        if (XIN) {                                                             \
          _Pragma("unroll") for (int g = 0; g < 4; ++g) {                      \
            f32x4 a;                                                           \
            _Pragma("unroll") for (int r = 0; r < 4; ++r)                      \
              a[r] = bias[g] + xw[g*3+0] * xr[P_][r*3+0]                       \
                             + xw[g*3+1] * xr[P_][r*3+1]                       \
                             + xw[g*3+2] * xr[P_][r*3+2];                      \
            xacc[1 - (P_)][g] = a;                                             \
          }                                                                    \
        } else {                                                               \
          _Pragma("unroll") for (int g = 0; g < 4; ++g) {                      \
            f32x4 a = {bias[g], bias[g], bias[g], bias[g]};                    \
            a = MFMA(xfr[P_][0], bih[g][0], a, 0, 0, 0);                       \
            a = MFMA(xfr[P_][1], bih[g][1], a, 0, 0, 0);                       \
            xacc[1 - (P_)][g] = a;                                             \
          }                                                                    \
        }                                                                      \
      }                                                                        \
      {                                                                        \
        int tp = (N_) + 3; if (tp > T_LEN - 1) tp = T_LEN - 1;                 \
        if (XIN) {                                                             \
          _Pragma("unroll") for (int r = 0; r < 4; ++r)                        \
            _Pragma("unroll") for (int i = 0; i < 3; ++i)                      \
              xr[P_][r*3+i] =                                                  \
                  x_f32[((size_t)(bbase + 4*cg + r) * T_LEN + tp) * 3 + i];    \
        } else {                                                               \
          const __bf16* px = seqb + xrow + (size_t)tp * HDIM;                  \
          xfr[P_][0] = *(const bf16x8*)(px + 8 * cg);                          \
          xfr[P_][1] = *(const bf16x8*)(px + 32 + 8 * cg);                     \
        }                                                                      \
      }                                                                        \
    } else {                                                                   \
      if ((N_) >= 2) {                                                         \
        const int tl = (N_) - 2;                                               \
        bf16x8 ah0 = *(const bf16x8*)&Hb[1][1 - (P_)][HADDR(nn, cg)];          \
        bf16x8 ah1 = *(const bf16x8*)&Hb[1][1 - (P_)][HADDR(nn, 4 + cg)];      \
        f32x4 accs[4];                                                         \
        _Pragma("unroll") for (int g = 0; g < 4; ++g) {                        \
          f32x4 a = xacc[P_][g];                                               \
          a = MFMA(ah0, bhh[g][0], a, 0, 0, 0);                                \
          a = MFMA(ah1, bhh[g][1], a, 0, 0, 0);                                \
          accs[g] = a;                                                         \
        }                                                                      \
        _Pragma("unroll") for (int r = 0; r < 4; ++r) {                        \
          float iv = sigm(accs[0][r]);                                         \
          float fv = sigm(accs[1][r]);                                         \
          float gv = tanh_(accs[2][r]);                                        \
          float ov = sigm(accs[3][r]);                                         \
          cell[r] = fv * cell[r] + iv * gv;                                    \
          float hv = ov * tanh_(cell[r]);                                      \
          __bf16 h1 = (__bf16)hv;                                              \
          int mrow = 4 * cg + r;                                               \
          Hb[1][P_][HADDR(mrow, uu >> 3) + (uu & 7)] = h1;                     \
          seqb[((size_t)(bbase + mrow) * T_LEN + tl) * HDIM + uu] = h1;        \
        }                                                                      \
      }                                                                        \
      /* tail: x-seed for t = N_-1 from upstream h0(N_-1), pre-barrier data */ \
      if ((N_) >= 1 && (N_) - 1 < T_LEN) {                                     \
        bf16x8 xh0 = *(const bf16x8*)&Hb[0][1 - (P_)][HADDR(nn, cg)];          \
        bf16x8 xh1 = *(const bf16x8*)&Hb[0][1 - (P_)][HADDR(nn, 4 + cg)];      \
        _Pragma("unroll") for (int g = 0; g < 4; ++g) {                        \
          f32x4 a = {bias[g], bias[g], bias[g], bias[g]};                      \
          a = MFMA(xh0, bih[g][0], a, 0, 0, 0);                                \
          a = MFMA(xh1, bih[g][1], a, 0, 0, 0);                                \
          xacc[1 - (P_)][g] = a;                                               \
        }                                                                      \
      }                                                                        \
    }                                                                          \
    BARRIER();                                                                 \
  }

template<int L0, bool XIN>
__global__ __launch_bounds__(512, 2)   // DO NOT raise (remat hazard)
void lstm_pairq(const float* __restrict__ x_f32,
                const float* __restrict__ w_ih0,
                const float* __restrict__ w_ih_rest,
                const float* __restrict__ w_hh,
                const float* __restrict__ b_ih,
                const float* __restrict__ b_hh,
                __bf16* __restrict__ seqb)
{
  const int tid  = threadIdx.x;
  const int lane = tid & 63;
  const int wv   = tid >> 6;
  const int set  = wv >> 2;       // 0,1 (wave-uniform)
  const int wq   = wv & 3;
  const int nn   = lane & 15;
  const int cg   = lane >> 4;
  const int bbase = blockIdx.x * 16;
  const int grow = 16 * wq + nn;
  const int uu   = grow;
  const int layer = L0 + set;

  __shared__ __align__(16) __bf16 Hb[2][2][1024];  // [set][parity], 4 KB

  bf16x8 bhh[4][2];
#pragma unroll
  for (int g = 0; g < 4; ++g)
#pragma unroll
    for (int kk = 0; kk < 2; ++kk) {
      const float* wp = w_hh + (size_t)layer * 256 * 64
                      + (size_t)(64 * g + grow) * 64 + kk * 32 + 8 * cg;
      bf16x8 t;
#pragma unroll
      for (int e = 0; e < 8; ++e) t[e] = (__bf16)wp[e];
      bhh[g][kk] = t;
    }
  bf16x8 bih[4][2];
  float xw[12];
  if (XIN && set == 0) {
#pragma unroll
    for (int g = 0; g < 4; ++g)
#pragma unroll
      for (int i = 0; i < 3; ++i) xw[g * 3 + i] = w_ih0[(64 * g + grow) * 3 + i];
  } else {
    const float* wih_l = w_ih_rest + (size_t)(layer - 1) * 256 * 64;
#pragma unroll
    for (int g = 0; g < 4; ++g)
#pragma unroll
      for (int kk = 0; kk < 2; ++kk) {
        const float* wp = wih_l + (size_t)(64 * g + grow) * 64 + kk * 32 + 8 * cg;
        bf16x8 t;
#pragma unroll
        for (int e = 0; e < 8; ++e) t[e] = (__bf16)wp[e];
        bih[g][kk] = t;
      }
  }
  float bias[4];
#pragma unroll
  for (int g = 0; g < 4; ++g) {
    int row = layer * 256 + 64 * g + grow;
    bias[g] = b_ih[row] + b_hh[row];
  }

  for (int q = tid; q < 4 * 1024; q += 512)
    ((__bf16*)Hb)[q] = (__bf16)0.f;

  float cell[4] = {0.f, 0.f, 0.f, 0.f};
  const size_t xrow = (size_t)(bbase + nn) * T_LEN * HDIM;

  f32x4 xacc[2][4];    // register x-seed, parity-indexed (macro-literal P_ only)
  float xr[2][12];     // set0 XIN queue
  bf16x8 xfr[2][2];    // set0 GIN queue (direct bf16 fragments)

  if (set == 0) {
    if (XIN) {
      float x0[12];
#pragma unroll
      for (int r = 0; r < 4; ++r)
#pragma unroll
        for (int i = 0; i < 3; ++i)
          x0[r*3+i] = x_f32[((size_t)(bbase + 4*cg + r) * T_LEN + 0) * 3 + i];
#pragma unroll
      for (int g = 0; g < 4; ++g) {
        f32x4 a;
#pragma unroll
        for (int r = 0; r < 4; ++r)
          a[r] = bias[g] + xw[g*3+0]*x0[r*3+0] + xw[g*3+1]*x0[r*3+1] + xw[g*3+2]*x0[r*3+2];
        xacc[0][g] = a;
      }
#pragma unroll
      for (int p = 0; p < 2; ++p)
#pragma unroll
        for (int r = 0; r < 4; ++r)
#pragma unroll
          for (int i = 0; i < 3; ++i)
            xr[p][r*3+i] = x_f32[((size_t)(bbase + 4*cg + r) * T_LEN + (p + 1)) * 3 + i];
    } else {
      const __bf16* px = seqb + xrow;
      bf16x8 x0a = *(const bf16x8*)(px + 8 * cg);
      bf16x8 x0b = *(const bf16x8*)(px + 32 + 8 * cg);
#pragma unroll
      for (int g = 0; g < 4; ++g) {
        f32x4 a = {bias[g], bias[g], bias[g], bias[g]};
        a = MFMA(x0a, bih[g][0], a, 0, 0, 0);
        a = MFMA(x0b, bih[g][1], a, 0, 0, 0);
        xacc[0][g] = a;
      }
#pragma unroll
      for (int p = 0; p < 2; ++p) {
        const __bf16* pq = seqb + xrow + (size_t)(p + 1) * HDIM;
        xfr[p][0] = *(const bf16x8*)(pq + 8 * cg);
        xfr[p][1] = *(const bf16x8*)(pq + 32 + 8 * cg);
      }
    }
  }
  __syncthreads();

  for (int n = 0; n < NSUP; n += 2) {
    SUPERQ(n,     0);
    SUPERQ(n + 1, 1);
  }
}

// -------------- Single-layer kernel (layer 4, bf16 h; writes hT f32) --------
#define STEP(T0, P)                                                            \
  {                                                                            \
    if (isA) {                                                                 \
      bf16x8 ah0 = *(const bf16x8*)&h_b[P][HADDR(nn, cg)];                     \
      bf16x8 ah1 = *(const bf16x8*)&h_b[P][HADDR(nn, 4 + cg)];                 \
      f32x4 accs[4];                                                           \
      _Pragma("unroll")                                                        \
      for (int g = 0; g < 4; ++g) {                                            \
        f32x4 a = accx[P][g][wq * 64 + lane];                                  \
        a = MFMA(ah0, bhh[g][0], a, 0, 0, 0);                                  \
        a = MFMA(ah1, bhh[g][1], a, 0, 0, 0);                                  \
        accs[g] = a;                                                           \
      }                                                                        \
      _Pragma("unroll")                                                        \
      for (int r = 0; r < 4; ++r) {                                            \
        float iv = sigm(accs[0][r]);                                           \
        float fv = sigm(accs[1][r]);                                           \
        float gv = tanh_(accs[2][r]);                                          \
        float ov = sigm(accs[3][r]);                                           \
        cell[r] = fv * cell[r] + iv * gv;                                      \
        float hv = ov * tanh_(cell[r]);                                        \
        __bf16 h1 = (__bf16)hv;                                                \
        int mrow = 4 * cg + r;                                                 \
        h_b[1 - (P)][HADDR(mrow, uu >> 3) + (uu & 7)] = h1;                    \
        if ((T0) == T_LEN - 1)                                                 \
          hT[(size_t)(bbase + mrow) * HDIM + uu] = hv;  /* f32, no quant */    \
      }                                                                        \
    } else {                                                                   \
      if ((T0) + 1 < T_LEN) {                                                  \
        _Pragma("unroll")                                                      \
        for (int g = 0; g < 4; ++g) {                                          \
          f32x4 a = {bias[g], bias[g], bias[g], bias[g]};                      \
          a = MFMA(xfr[P][0], bih[g][0], a, 0, 0, 0);                          \
          a = MFMA(xfr[P][1], bih[g][1], a, 0, 0, 0);                          \
          accx[1 - (P)][g][wq * 64 + lane] = a;                                \
        }                                                                      \
      }                                                                        \
      {                                                                        \
        int tp = (T0) + 3; if (tp >= T_LEN) tp = T_LEN - 1;                    \
        const __bf16* px = seqb + xrow + (size_t)tp * HDIM;                    \
        xfr[P][0] = *(const bf16x8*)(px + 8 * cg);                             \
        xfr[P][1] = *(const bf16x8*)(px + 32 + 8 * cg);                        \
      }                                                                        \
    }                                                                          \
    BARRIER();                                                                 \
  }

__global__ __launch_bounds__(512, 2)
void lstm_single(const float* __restrict__ w_ih,
                 const float* __restrict__ w_hh,
                 const float* __restrict__ b_ih,
                 const float* __restrict__ b_hh,
                 const __bf16* __restrict__ seqb,
                 float* __restrict__ hT)
{
    const int tid  = threadIdx.x;
    const int lane = tid & 63;
    const int wv   = tid >> 6;
    const bool isA = (wv < 4);
    const int wq   = wv & 3;
    const int nn   = lane & 15;
    const int cg   = lane >> 4;
    const int bbase = blockIdx.x * 16;
    const int grow = 16 * wq + nn;
    const int uu   = grow;

    __shared__ __align__(16) __bf16 h_b[2][1024];        // 4 KB
    __shared__ __align__(16) f32x4 accx[2][4][256];      // 32 KB

    bf16x8 bhh[4][2];
    bf16x8 bih[4][2];
    float bias[4];
    if (isA) {
#pragma unroll
      for (int g = 0; g < 4; ++g)
#pragma unroll
        for (int kk = 0; kk < 2; ++kk) {
          const float* wp = w_hh + (size_t)(64 * g + grow) * 64 + kk * 32 + 8 * cg;
          bf16x8 t;
#pragma unroll
          for (int e = 0; e < 8; ++e) t[e] = (__bf16)wp[e];
          bhh[g][kk] = t;
        }
    } else {
#pragma unroll
      for (int g = 0; g < 4; ++g) {
        int row = 64 * g + grow;
        bias[g] = b_ih[row] + b_hh[row];
      }
#pragma unroll
      for (int g = 0; g < 4; ++g)
#pragma unroll
        for (int kk = 0; kk < 2; ++kk) {
          const float* wp = w_ih + (size_t)(64 * g + grow) * 64 + kk * 32 + 8 * cg;
          bf16x8 t;
#pragma unroll
          for (int e = 0; e < 8; ++e) t[e] = (__bf16)wp[e];
          bih[g][kk] = t;
        }
    }

    for (int q = tid; q < 2048; q += 512)
      ((__bf16*)h_b)[q] = (__bf16)0.f;

    float cell[4] = {0.f, 0.f, 0.f, 0.f};
    const size_t xrow = (size_t)(bbase + nn) * T_LEN * HDIM;
    bf16x8 xfr[2][2];

    if (!isA) {
      const __bf16* px = seqb + xrow;
      bf16x8 x0a = *(const bf16x8*)(px + 8 * cg);
      bf16x8 x0b = *(const bf16x8*)(px + 32 + 8 * cg);
#pragma unroll
      for (int g = 0; g < 4; ++g) {
        f32x4 a = {bias[g], bias[g], bias[g], bias[g]};
        a = MFMA(x0a, bih[g][0], a, 0, 0, 0);
        a = MFMA(x0b, bih[g][1], a, 0, 0, 0);
        accx[0][g][wq * 64 + lane] = a;
      }
#pragma unroll
      for (int p = 0; p < 2; ++p) {
        const __bf16* pq = seqb + xrow + (size_t)(p + 1) * HDIM;
        xfr[p][0] = *(const bf16x8*)(pq + 8 * cg);
        xfr[p][1] = *(const bf16x8*)(pq + 32 + 8 * cg);
      }
    }
    __syncthreads();

    if (isA) __builtin_amdgcn_s_setprio(1);
    for (int t = 0; t < T_LEN; t += 2) {
      STEP(t, 0);
      STEP(t + 1, 1);
    }
    if (isA) __builtin_amdgcn_s_setprio(0);
}

// FC head: out[b] = fc2_b + fc2_w . relu(fc1_b + fc1_w . hT[b]); hT is f32.
__global__ __launch_bounds__(256, 1)
void fc_head(const float* __restrict__ hT,
             const float* __restrict__ fc1_w, const float* __restrict__ fc1_b,
             const float* __restrict__ fc2_w, const float* __restrict__ fc2_b,
             float* __restrict__ out)
{
    __shared__ float w1[FC1 * HDIM];
    __shared__ float b1[FC1];
    __shared__ float w2[FC1];
    const int tid = threadIdx.x;
    for (int i = tid; i < FC1 * HDIM; i += 256) w1[i] = fc1_w[i];
    if (tid < FC1) { b1[tid] = fc1_b[tid]; w2[tid] = fc2_w[tid]; }
    __syncthreads();

    const int b = blockIdx.x * 256 + tid;
    float h[HDIM];
    const float4* hp = (const float4*)(hT + (size_t)b * HDIM);
#pragma unroll
    for (int q = 0; q < 16; ++q) {
      float4 v = hp[q];
      h[q*4+0] = v.x; h[q*4+1] = v.y; h[q*4+2] = v.z; h[q*4+3] = v.w;
    }
    float acc2 = fc2_b[0];
    for (int m = 0; m < FC1; ++m) {
      float a = b1[m];
#pragma unroll
      for (int q = 0; q < HDIM; ++q) a += w1[m * HDIM + q] * h[q];
      acc2 += w2[m] * fmaxf(a, 0.0f);
    }
    out[b] = acc2;
}

extern "C" void kernel_launch(void* const* d_in, const int* in_sizes, int n_in,
                              void* d_out, int out_size, void* d_ws, size_t ws_size,
                              hipStream_t stream) {
    const float* x         = (const float*)d_in[0];
    const float* w_ih0     = (const float*)d_in[1];
    const float* w_ih_rest = (const float*)d_in[2];
    const float* w_hh      = (const float*)d_in[3];
    const float* b_ih      = (const float*)d_in[4];
    const float* b_hh      = (const float*)d_in[5];
    const float* fc1_w     = (const float*)d_in[6];
    const float* fc1_b     = (const float*)d_in[7];
    const float* fc2_w     = (const float*)d_in[8];
    const float* fc2_b     = (const float*)d_in[9];
    float* out = (float*)d_out;

    __bf16* seqb = (__bf16*)d_ws;                                   // 128 MiB
    float* hT = (float*)(seqb + (size_t)B_TOT * T_LEN * HDIM);      // 512 KiB

    dim3 grid(B_TOT / 16), block(512);
    // layers 0+1, skew-2 pair; writes seq1 (bf16)
    lstm_pairq<0, true><<<grid, block, 0, stream>>>(
        x, w_ih0, w_ih_rest, w_hh, b_ih, b_hh, seqb);
    // layers 2+3, skew-2 pair; reads seq1 / writes seq3 in-place (gap >= 5)
    lstm_pairq<2, false><<<grid, block, 0, stream>>>(
        x, w_ih0, w_ih_rest, w_hh, b_ih, b_hh, seqb);
    // layer 4; reads seq3, writes hT f32 (A-wave epilogue, no quantization)
    lstm_single<<<grid, block, 0, stream>>>(
        w_ih_rest + (size_t)3 * 256 * HDIM,
        w_hh + (size_t)4 * 256 * HDIM,
        b_ih + (size_t)4 * 256,
        b_hh + (size_t)4 * 256,
        seqb, hT);
    fc_head<<<dim3(B_TOT / 256), dim3(256), 0, stream>>>(
        hT, fc1_w, fc1_b, fc2_w, fc2_b, out);
}